// Round 11
// baseline (45.079 us; speedup 1.0000x reference)
//
#include <hip/hip_runtime.h>

typedef __bf16 bf16x8 __attribute__((ext_vector_type(8)));
typedef float  f32x16 __attribute__((ext_vector_type(16)));

#define NI 256
#define NT 256
#define NL 32
#define NE 128
#define HW 49
#define NEG_INF (-3.0e38f)

// ws layout (bf16), validated R5/R8-R10:
//  wsA: frag gw = (i*2+mt)*8+ks, elem (gw*64+lane)*8+j
//       = img[i, e=ks*16+(lane>>5)*8+j, hw=min(mt*32+(lane&31),48)]   (4 MB)
//  wsB: frag gw = t*8+ks, elem (gw*64+lane)*8+j
//       = txt[t, l=lane&31, e=ks*16+(lane>>5)*8+j]                    (2 MB)

// ---------- pre-kernel: fp32 -> bf16 MFMA-fragment layout ----------
__global__ __launch_bounds__(256, 4)
void prep_kernel(const float* __restrict__ img,
                 const float* __restrict__ txt,
                 __bf16* __restrict__ wsA,
                 __bf16* __restrict__ wsB)
{
    const int tid  = threadIdx.x;
    const int wave = tid >> 6, lane = tid & 63;
    const int ml   = lane & 31, h = lane >> 5;
    const int bid  = blockIdx.x;
    if (bid < 1024) {                       // A-part: 4096 waves
        int gw = bid * 4 + wave;            // (i, mt, ks)
        int i  = gw >> 4, mt = (gw >> 3) & 1, ks = gw & 7;
        int m  = mt * 32 + ml; if (m > HW - 1) m = HW - 1;
        int e0 = ks * 16 + h * 8;
        const float* p = img + ((size_t)i * NE + e0) * HW + m;
        union { __bf16 b[8]; int4 v; } u;
        #pragma unroll
        for (int j = 0; j < 8; ++j) u.b[j] = (__bf16)p[j * HW];
        *(int4*)(wsA + ((size_t)gw * 64 + lane) * 8) = u.v;
    } else {                                // B-part: 2048 waves
        int gw = (bid - 1024) * 4 + wave;   // (t, ks)
        int t  = gw >> 3, ks = gw & 7;
        int e0 = ks * 16 + h * 8;
        const float* p = txt + ((size_t)t * NL + ml) * NE + e0;
        float4 f0 = *(const float4*)p;
        float4 f1 = *(const float4*)(p + 4);
        union { __bf16 b[8]; int4 v; } u;
        u.b[0] = (__bf16)f0.x; u.b[1] = (__bf16)f0.y;
        u.b[2] = (__bf16)f0.z; u.b[3] = (__bf16)f0.w;
        u.b[4] = (__bf16)f1.x; u.b[5] = (__bf16)f1.y;
        u.b[6] = (__bf16)f1.z; u.b[7] = (__bf16)f1.w;
        *(int4*)(wsB + ((size_t)gw * 64 + lane) * 8) = u.v;
    }
}

// 8 fragment loads (8 KB/wave), issued via volatile asm: cannot be sunk or
// serialized by the compiler; completion is claimed ONLY by explicit vmcnt.
__device__ __forceinline__ void gload8(bf16x8* dst, const __bf16* base)
{
    const __bf16* base2 = base + 2048;      // frags 4..7 (offset 4096 B)
    asm volatile(
        "global_load_dwordx4 %0, %8, off\n\t"
        "global_load_dwordx4 %1, %8, off offset:1024\n\t"
        "global_load_dwordx4 %2, %8, off offset:2048\n\t"
        "global_load_dwordx4 %3, %8, off offset:3072\n\t"
        "global_load_dwordx4 %4, %9, off\n\t"
        "global_load_dwordx4 %5, %9, off offset:1024\n\t"
        "global_load_dwordx4 %6, %9, off offset:2048\n\t"
        "global_load_dwordx4 %7, %9, off offset:3072"
        : "=v"(dst[0]), "=v"(dst[1]), "=v"(dst[2]), "=v"(dst[3]),
          "=v"(dst[4]), "=v"(dst[5]), "=v"(dst[6]), "=v"(dst[7])
        : "v"(base), "v"(base2)
        : "memory");
}

#define VMWAIT8 { asm volatile("s_waitcnt vmcnt(8)" ::: "memory"); \
                  __builtin_amdgcn_sched_barrier(0); }
#define VMWAIT0 { asm volatile("s_waitcnt vmcnt(0)" ::: "memory"); \
                  __builtin_amdgcn_sched_barrier(0); }

// ---------- main kernel ----------
// Block: 4 waves = 4 images; chunk = 32 texts. Grid 512 = 64 ig x 8 tc
// = 2 blocks/CU, zero tail, ZERO barriers. Per text: 8 asm loads (in flight
// across the previous text's compute, counted vmcnt(8)) -> 16 MFMA -> fmax
// tree -> 1 wave-private ds_write. ~195 VGPR: nothing for regalloc to sink.
__global__ __launch_bounds__(256, 2)
void clip_match_kernel(const __bf16* __restrict__ wsA,
                       const __bf16* __restrict__ wsB,
                       const int* __restrict__ tlen,
                       const float* __restrict__ nlt,
                       float* __restrict__ out)
{
    const int tid  = threadIdx.x;
    const int wave = tid >> 6, lane = tid & 63;
    const int ml   = lane & 31, h = lane >> 5;
    const int tb   = blockIdx.x & 7;     // text chunk (32 texts)
    const int ig   = blockIdx.x >> 3;    // image group (4 images)
    const int im   = ig * 4 + wave;      // this wave's image

    // per-(text): 64 partial maxima (h*32+col); stride 68 breaks epi banks
    __shared__ __align__(16) float colmax[4][NL][68];   // ~34 KB, wave-private

    const __bf16* pa   = wsA + (size_t)im * 8192 + lane * 8;
    const __bf16* csrc = wsB + (size_t)tb * NL * 4096 + lane * 8;

    bf16x8 afr0[8], afr1[8];             // m-tiles 0/1 of this image
    bf16x8 b0[8], b1[8];
    gload8(afr0, pa);                    // 8  outstanding
    gload8(afr1, pa + 4096);             // 16
    gload8(b0, csrc);                    // 24

#define COMPUTE(bfr, t)                                                     \
    {                                                                       \
        f32x16 acc0 = (f32x16)(0.f), acc1 = (f32x16)(0.f);                  \
        _Pragma("unroll")                                                   \
        for (int ks = 0; ks < 8; ++ks) {                                    \
            acc0 = __builtin_amdgcn_mfma_f32_32x32x16_bf16(                 \
                afr0[ks], bfr[ks], acc0, 0, 0, 0);                          \
            acc1 = __builtin_amdgcn_mfma_f32_32x32x16_bf16(                 \
                afr1[ks], bfr[ks], acc1, 0, 0, 0);                          \
        }                                                                   \
        /* partial max over this h-half's rows; C/D: col=lane&31,          \
           row r2=(reg&3)+8*(reg>>2)+4*h; acc0: m=r2 (all 16 valid);       \
           acc1: m=32+r2 -> regs 0..7, plus reg8 (m=48) iff h==0 */        \
        float t0[8];                                                        \
        _Pragma("unroll")                                                   \
        for (int k = 0; k < 8; ++k) t0[k] = fmaxf(acc0[2*k], acc0[2*k+1]);  \
        float t1[4];                                                        \
        _Pragma("unroll")                                                   \
        for (int k = 0; k < 4; ++k) t1[k] = fmaxf(t0[2*k], t0[2*k+1]);      \
        float a0m = fmaxf(fmaxf(t1[0], t1[1]), fmaxf(t1[2], t1[3]));        \
        float u0[4];                                                        \
        _Pragma("unroll")                                                   \
        for (int k = 0; k < 4; ++k) u0[k] = fmaxf(acc1[2*k], acc1[2*k+1]);  \
        float a1m = fmaxf(fmaxf(u0[0], u0[1]), fmaxf(u0[2], u0[3]));        \
        float ex  = (h == 0) ? acc1[8] : NEG_INF;                           \
        colmax[wave][t][lane] = fmaxf(fmaxf(a0m, a1m), ex);                 \
    }

    #pragma unroll 1
    for (int it = 0; it < 15; ++it) {
        const int t = 2 * it;
        gload8(b1, csrc + (size_t)(t + 1) * 4096);
        VMWAIT8                          // b0 ready (afr drained at it=0)
        COMPUTE(b0, t)
        gload8(b0, csrc + (size_t)(t + 2) * 4096);
        VMWAIT8                          // b1 ready
        COMPUTE(b1, t + 1)
    }
    gload8(b1, csrc + (size_t)31 * 4096);
    VMWAIT8
    COMPUTE(b0, 30)
    VMWAIT0
    COMPUTE(b1, 31)
#undef COMPUTE

    // ---- epilogue: merge h-halves, sum 32 cols, write both mirrors ----
    {
        const float scale = expf(nlt[0]);
        const int t = ml;                    // text within chunk
        const float* r0 = &colmax[wave][t][h * 16];        // h-part 0 slice
        const float* r1 = &colmax[wave][t][32 + h * 16];   // h-part 1 slice
        float4 a0 = *(const float4*)(r0 + 0);
        float4 a1 = *(const float4*)(r0 + 4);
        float4 a2 = *(const float4*)(r0 + 8);
        float4 a3 = *(const float4*)(r0 + 12);
        float4 c0 = *(const float4*)(r1 + 0);
        float4 c1 = *(const float4*)(r1 + 4);
        float4 c2 = *(const float4*)(r1 + 8);
        float4 c3 = *(const float4*)(r1 + 12);
        float s = (fmaxf(a0.x, c0.x) + fmaxf(a0.y, c0.y))
                + (fmaxf(a0.z, c0.z) + fmaxf(a0.w, c0.w))
                + (fmaxf(a1.x, c1.x) + fmaxf(a1.y, c1.y))
                + (fmaxf(a1.z, c1.z) + fmaxf(a1.w, c1.w))
                + (fmaxf(a2.x, c2.x) + fmaxf(a2.y, c2.y))
                + (fmaxf(a2.z, c2.z) + fmaxf(a2.w, c2.w))
                + (fmaxf(a3.x, c3.x) + fmaxf(a3.y, c3.y))
                + (fmaxf(a3.z, c3.z) + fmaxf(a3.w, c3.w));
        s += __shfl_xor(s, 32);              // other 16-col slice
        if (h == 0) {
            int tg = tb * NL + t;
            float v = s * scale / (float)tlen[tg];
            out[im * NT + tg] = v;              // logits_per_image[i,t]
            out[NI * NT + tg * NI + im] = v;    // logits_per_text[t,i]
        }
    }
}

extern "C" void kernel_launch(void* const* d_in, const int* in_sizes, int n_in,
                              void* d_out, int out_size, void* d_ws, size_t ws_size,
                              hipStream_t stream)
{
    const float* img  = (const float*)d_in[0];
    const float* txt  = (const float*)d_in[1];
    const int*   tlen = (const int*)d_in[2];
    const float* nlt  = (const float*)d_in[3];
    float* out = (float*)d_out;

    __bf16* wsA = (__bf16*)d_ws;                 // 4 MB
    __bf16* wsB = wsA + (size_t)4096 * 512;      // 2 MB

    prep_kernel<<<dim3(1536), dim3(256), 0, stream>>>(img, txt, wsA, wsB);
    clip_match_kernel<<<dim3(512), dim3(256), 0, stream>>>(wsA, wsB, tlen, nlt, out);
}

// Round 12
// 44.647 us; speedup vs baseline: 1.0097x; 1.0097x over previous
//
#include <hip/hip_runtime.h>

typedef __bf16 bf16x8 __attribute__((ext_vector_type(8)));
typedef float  f32x16 __attribute__((ext_vector_type(16)));

#define NI 256
#define NT 256
#define NL 32
#define NE 128
#define HW 49
#define NEG_INF (-3.0e38f)

// ws layout (bf16), validated R5/R8+:
//  wsA: frag gw = (i*2+mt)*8+ks, elem (gw*64+lane)*8+j
//       = img[i, e=ks*16+(lane>>5)*8+j, hw=min(mt*32+(lane&31),48)]   (4 MB)
//  wsB: frag gw = t*8+ks, elem (gw*64+lane)*8+j
//       = txt[t, l=lane&31, e=ks*16+(lane>>5)*8+j]                    (2 MB)

// ---------- pre-kernel: fp32 -> bf16 MFMA-fragment layout ----------
__global__ __launch_bounds__(256, 4)
void prep_kernel(const float* __restrict__ img,
                 const float* __restrict__ txt,
                 __bf16* __restrict__ wsA,
                 __bf16* __restrict__ wsB)
{
    const int tid  = threadIdx.x;
    const int wave = tid >> 6, lane = tid & 63;
    const int ml   = lane & 31, h = lane >> 5;
    const int bid  = blockIdx.x;
    if (bid < 1024) {                       // A-part: 4096 waves
        int gw = bid * 4 + wave;            // (i, mt, ks)
        int i  = gw >> 4, mt = (gw >> 3) & 1, ks = gw & 7;
        int m  = mt * 32 + ml; if (m > HW - 1) m = HW - 1;
        int e0 = ks * 16 + h * 8;
        const float* p = img + ((size_t)i * NE + e0) * HW + m;
        union { __bf16 b[8]; int4 v; } u;
        #pragma unroll
        for (int j = 0; j < 8; ++j) u.b[j] = (__bf16)p[j * HW];
        *(int4*)(wsA + ((size_t)gw * 64 + lane) * 8) = u.v;
    } else {                                // B-part: 2048 waves
        int gw = (bid - 1024) * 4 + wave;   // (t, ks)
        int t  = gw >> 3, ks = gw & 7;
        int e0 = ks * 16 + h * 8;
        const float* p = txt + ((size_t)t * NL + ml) * NE + e0;
        float4 f0 = *(const float4*)p;
        float4 f1 = *(const float4*)(p + 4);
        union { __bf16 b[8]; int4 v; } u;
        u.b[0] = (__bf16)f0.x; u.b[1] = (__bf16)f0.y;
        u.b[2] = (__bf16)f0.z; u.b[3] = (__bf16)f0.w;
        u.b[4] = (__bf16)f1.x; u.b[5] = (__bf16)f1.y;
        u.b[6] = (__bf16)f1.z; u.b[7] = (__bf16)f1.w;
        *(int4*)(wsB + ((size_t)gw * 64 + lane) * 8) = u.v;
    }
}

#define GLDS(gp, lp) __builtin_amdgcn_global_load_lds(                     \
        (const __attribute__((address_space(1))) void*)(gp),               \
        (__attribute__((address_space(3))) void*)(lp), 16, 0, 0)

// ---------- main kernel: 8-phase-style schedule (T3+T4+T5) ----------
// Block: 4 waves = 4 images; chunk 32 texts; rounds of 4 texts, FULLY
// unrolled (32 phases). Phase = {8 ds_read_b128 || 2 global_load_lds
// (consumed one full round later) -> raw s_barrier -> setprio(1) 16 MFMA
// setprio(0) -> fmax tree into reg cmax[t] -> raw s_barrier}. One explicit
// vmcnt(0) per round (drains only round-old loads). RAW barriers: no
// compiler-inserted vmcnt(0) drain per phase (the m97 stall).
// Grid 512 = 64 ig x 8 tb = 2 blocks/CU, zero tail. LDS 64KB (2 blocks/CU).
__global__ __launch_bounds__(256, 2)
void clip_match_kernel(const __bf16* __restrict__ wsA,
                       const __bf16* __restrict__ wsB,
                       const int* __restrict__ tlen,
                       const float* __restrict__ nlt,
                       float* __restrict__ out)
{
    const int tid  = threadIdx.x;
    const int wave = tid >> 6, lane = tid & 63;
    const int ml   = lane & 31, h = lane >> 5;
    const int tb   = blockIdx.x & 7;     // text chunk (32 texts); == XCD id
    const int ig   = blockIdx.x >> 3;    // image group (4 images)
    const int im   = ig * 4 + wave;      // this wave's image

    __shared__ __align__(16) __bf16 buf[2][4 * 4096];   // 2 x 32 KB (4 texts)

    // ---- A fragments: this wave's image, fragment-linear, 16 dwordx4 ----
    bf16x8 afr0[8], afr1[8];
    {
        const __bf16* pa = wsA + (size_t)im * 8192 + (size_t)lane * 8;
        #pragma unroll
        for (int ks = 0; ks < 8; ++ks) {
            afr0[ks] = *(const bf16x8*)(pa + ks * 512);
            afr1[ks] = *(const bf16x8*)(pa + 4096 + ks * 512);
        }
    }

    const __bf16* csrc = wsB + (size_t)tb * NL * 4096;

    // ---- prologue: stage round 0 (32 KB); 8 segs of 1 KB per wave ----
    #pragma unroll
    for (int q = 0; q < 8; ++q) {
        int s = wave * 8 + q;
        GLDS(csrc + s * 512 + lane * 8, &buf[0][s * 512] + lane * 8);
    }
    asm volatile("s_waitcnt vmcnt(0)" ::: "memory");
    __builtin_amdgcn_sched_barrier(0);
    __builtin_amdgcn_s_barrier();

    float cmax[NL];                       // static-indexed (full unroll)

    #pragma unroll
    for (int rnd = 0; rnd < 8; ++rnd) {
        const __bf16* __restrict__ bsrc = buf[rnd & 1];
        __bf16* nbuf = buf[(rnd & 1) ^ 1];
        const __bf16* nsrc = csrc + (size_t)(rnd + 1) * 16384;
        #pragma unroll
        for (int ts = 0; ts < 4; ++ts) {
            const int t = rnd * 4 + ts;
            // ds-load this phase's B fragments (compiler handles lgkmcnt)
            bf16x8 bfrag[8];
            #pragma unroll
            for (int ks = 0; ks < 8; ++ks)
                bfrag[ks] = *(const bf16x8*)(bsrc + ts * 4096
                                             + (ks * 64 + lane) * 8);
            // stage text ts of NEXT round (read one full round from now)
            if (rnd < 7) {
                #pragma unroll
                for (int q = 0; q < 2; ++q) {
                    int s = ts * 8 + wave * 2 + q;
                    GLDS(nsrc + s * 512 + lane * 8,
                         nbuf + s * 512 + lane * 8);
                }
            }
            __builtin_amdgcn_s_barrier();              // BAR1 (raw)
            __builtin_amdgcn_s_setprio(1);
            f32x16 acc0 = (f32x16)(0.f), acc1 = (f32x16)(0.f);
            #pragma unroll
            for (int ks = 0; ks < 8; ++ks) {
                acc0 = __builtin_amdgcn_mfma_f32_32x32x16_bf16(
                    afr0[ks], bfrag[ks], acc0, 0, 0, 0);
                acc1 = __builtin_amdgcn_mfma_f32_32x32x16_bf16(
                    afr1[ks], bfrag[ks], acc1, 0, 0, 0);
            }
            __builtin_amdgcn_s_setprio(0);
            // partial max over this h-half's rows; C/D: col=lane&31,
            // row r2=(reg&3)+8*(reg>>2)+4*h; acc0: m=r2 (all 16 valid);
            // acc1: m=32+r2 -> regs 0..7, plus reg8 (m=48) iff h==0
            {
                float t0[8];
                #pragma unroll
                for (int k = 0; k < 8; ++k)
                    t0[k] = fmaxf(acc0[2*k], acc0[2*k+1]);
                float t1[4];
                #pragma unroll
                for (int k = 0; k < 4; ++k)
                    t1[k] = fmaxf(t0[2*k], t0[2*k+1]);
                float a0m = fmaxf(fmaxf(t1[0], t1[1]), fmaxf(t1[2], t1[3]));
                float u0[4];
                #pragma unroll
                for (int k = 0; k < 4; ++k)
                    u0[k] = fmaxf(acc1[2*k], acc1[2*k+1]);
                float a1m = fmaxf(fmaxf(u0[0], u0[1]), fmaxf(u0[2], u0[3]));
                float ex  = (h == 0) ? acc1[8] : NEG_INF;
                cmax[t]   = fmaxf(fmaxf(a0m, a1m), ex);
            }
            if (ts == 3 && rnd < 7) {      // round boundary: stage must land
                asm volatile("s_waitcnt vmcnt(0)" ::: "memory");
                __builtin_amdgcn_sched_barrier(0);
            }
            __builtin_amdgcn_s_barrier();              // BAR2 (raw)
        }
    }

    // ---- epilogue: dump cmax to LDS scratch (reuses buf), reduce, write ----
    {
        float* scr = ((float*)&buf[0][0]) + wave * (NL * 66);  // wave-private
        #pragma unroll
        for (int t = 0; t < NL; ++t)
            scr[t * 66 + lane] = cmax[t];
        const float scale = expf(nlt[0]);
        const int t = ml;                    // text within chunk
        const float* r0 = &scr[t * 66 + h * 16];        // h-part 0 slice
        const float* r1 = &scr[t * 66 + 32 + h * 16];   // h-part 1 slice
        float4 a0 = *(const float4*)(r0 + 0);
        float4 a1 = *(const float4*)(r0 + 4);
        float4 a2 = *(const float4*)(r0 + 8);
        float4 a3 = *(const float4*)(r0 + 12);
        float4 c0 = *(const float4*)(r1 + 0);
        float4 c1 = *(const float4*)(r1 + 4);
        float4 c2 = *(const float4*)(r1 + 8);
        float4 c3 = *(const float4*)(r1 + 12);
        float s = (fmaxf(a0.x, c0.x) + fmaxf(a0.y, c0.y))
                + (fmaxf(a0.z, c0.z) + fmaxf(a0.w, c0.w))
                + (fmaxf(a1.x, c1.x) + fmaxf(a1.y, c1.y))
                + (fmaxf(a1.z, c1.z) + fmaxf(a1.w, c1.w))
                + (fmaxf(a2.x, c2.x) + fmaxf(a2.y, c2.y))
                + (fmaxf(a2.z, c2.z) + fmaxf(a2.w, c2.w))
                + (fmaxf(a3.x, c3.x) + fmaxf(a3.y, c3.y))
                + (fmaxf(a3.z, c3.z) + fmaxf(a3.w, c3.w));
        s += __shfl_xor(s, 32);              // other 16-col slice
        if (h == 0) {
            int tg = tb * NL + t;
            float v = s * scale / (float)tlen[tg];
            out[im * NT + tg] = v;              // logits_per_image[i,t]
            out[NI * NT + tg * NI + im] = v;    // logits_per_text[t,i]
        }
    }
}

extern "C" void kernel_launch(void* const* d_in, const int* in_sizes, int n_in,
                              void* d_out, int out_size, void* d_ws, size_t ws_size,
                              hipStream_t stream)
{
    const float* img  = (const float*)d_in[0];
    const float* txt  = (const float*)d_in[1];
    const int*   tlen = (const int*)d_in[2];
    const float* nlt  = (const float*)d_in[3];
    float* out = (float*)d_out;

    __bf16* wsA = (__bf16*)d_ws;                 // 4 MB
    __bf16* wsB = wsA + (size_t)4096 * 512;      // 2 MB

    prep_kernel<<<dim3(1536), dim3(256), 0, stream>>>(img, txt, wsA, wsB);
    clip_match_kernel<<<dim3(512), dim3(256), 0, stream>>>(wsA, wsB, tlen, nlt, out);
}

// Round 13
// 44.078 us; speedup vs baseline: 1.0227x; 1.0129x over previous
//
#include <hip/hip_runtime.h>

typedef __bf16 bf16x8 __attribute__((ext_vector_type(8)));
typedef float  f32x4  __attribute__((ext_vector_type(4)));

#define NI 256
#define NT 256
#define NL 32
#define NE 128
#define HW 49
#define NEG_INF (-3.0e38f)

// ws layout (bf16), 16x16x32 fragment-linear:
//  wsA: frag gw = (i*4+mf)*4+ks, elem (gw*64+lane)*8+j
//       = img[i, e=ks*32+(lane>>4)*8+j, hw=min(mf*16+(lane&15),48)]   (4 MB)
//  wsB: frag gw = t*8+nf*4+ks, elem (gw*64+lane)*8+j
//       = txt[t, l=nf*16+(lane&15), e=ks*32+(lane>>4)*8+j]            (2 MB)

// ---------- pre-kernel: fp32 -> bf16 MFMA-fragment layout ----------
__global__ __launch_bounds__(256, 4)
void prep_kernel(const float* __restrict__ img,
                 const float* __restrict__ txt,
                 __bf16* __restrict__ wsA,
                 __bf16* __restrict__ wsB)
{
    const int tid  = threadIdx.x;
    const int wave = tid >> 6, lane = tid & 63;
    const int lo   = lane & 15, hi = lane >> 4;
    const int bid  = blockIdx.x;
    if (bid < 1024) {                       // A-part: 4096 waves
        int gw = bid * 4 + wave;            // (i, mf, ks)
        int i  = gw >> 4, mf = (gw >> 2) & 3, ks = gw & 3;
        int m  = mf * 16 + lo; if (m > HW - 1) m = HW - 1;
        int e0 = ks * 32 + hi * 8;
        const float* p = img + ((size_t)i * NE + e0) * HW + m;
        union { __bf16 b[8]; int4 v; } u;
        #pragma unroll
        for (int j = 0; j < 8; ++j) u.b[j] = (__bf16)p[j * HW];
        *(int4*)(wsA + ((size_t)gw * 64 + lane) * 8) = u.v;
    } else {                                // B-part: 2048 waves
        int gw = (bid - 1024) * 4 + wave;   // (t, nf, ks)
        int t  = gw >> 3, nf = (gw >> 2) & 1, ks = gw & 3;
        int l  = nf * 16 + lo;
        int e0 = ks * 32 + hi * 8;
        const float* p = txt + ((size_t)t * NL + l) * NE + e0;
        float4 f0 = *(const float4*)p;
        float4 f1 = *(const float4*)(p + 4);
        union { __bf16 b[8]; int4 v; } u;
        u.b[0] = (__bf16)f0.x; u.b[1] = (__bf16)f0.y;
        u.b[2] = (__bf16)f0.z; u.b[3] = (__bf16)f0.w;
        u.b[4] = (__bf16)f1.x; u.b[5] = (__bf16)f1.y;
        u.b[6] = (__bf16)f1.z; u.b[7] = (__bf16)f1.w;
        *(int4*)(wsB + ((size_t)gw * 64 + lane) * 8) = u.v;
    }
}

// 8 fragment loads (8 KB/wave) via volatile asm: cannot be sunk; completion
// claimed ONLY by explicit counted vmcnt.
__device__ __forceinline__ void gload8(bf16x8* dst, const __bf16* base)
{
    const __bf16* base2 = base + 2048;
    asm volatile(
        "global_load_dwordx4 %0, %8, off\n\t"
        "global_load_dwordx4 %1, %8, off offset:1024\n\t"
        "global_load_dwordx4 %2, %8, off offset:2048\n\t"
        "global_load_dwordx4 %3, %8, off offset:3072\n\t"
        "global_load_dwordx4 %4, %9, off\n\t"
        "global_load_dwordx4 %5, %9, off offset:1024\n\t"
        "global_load_dwordx4 %6, %9, off offset:2048\n\t"
        "global_load_dwordx4 %7, %9, off offset:3072"
        : "=v"(dst[0]), "=v"(dst[1]), "=v"(dst[2]), "=v"(dst[3]),
          "=v"(dst[4]), "=v"(dst[5]), "=v"(dst[6]), "=v"(dst[7])
        : "v"(base), "v"(base2)
        : "memory");
}

#define VMWAIT8 { asm volatile("s_waitcnt vmcnt(8)" ::: "memory"); \
                  __builtin_amdgcn_sched_barrier(0); }
#define VMWAIT0 { asm volatile("s_waitcnt vmcnt(0)" ::: "memory"); \
                  __builtin_amdgcn_sched_barrier(0); }

// ---------- main kernel: 16x16x32, 8 INDEPENDENT acc chains / text ----------
// Block: 4 waves = 4 images; chunk 32 texts; grid 512 = 64 ig x 8 tb
// = 2 blocks/CU, zero tail, ZERO barriers. Per text: 8 asm loads (pipelined
// 1 text deep, counted vmcnt) -> 32 MFMA in 8 length-4 chains (dep distance
// 8 instrs) -> fmax tree -> 2 predicated ds_writes. Chain experiment: 16
// chains/SIMD vs the 2-4 of R6-R12.
__global__ __launch_bounds__(256, 2)
void clip_match_kernel(const __bf16* __restrict__ wsA,
                       const __bf16* __restrict__ wsB,
                       const int* __restrict__ tlen,
                       const float* __restrict__ nlt,
                       float* __restrict__ out)
{
    const int tid  = threadIdx.x;
    const int wave = tid >> 6, lane = tid & 63;
    const int lo   = lane & 15, hi = lane >> 4;
    const int ml   = lane & 31, h = lane >> 5;
    const int tb   = blockIdx.x & 7;     // text chunk (32 texts)
    const int ig   = blockIdx.x >> 3;    // image group (4 images)
    const int im   = ig * 4 + wave;      // this wave's image

    __shared__ __align__(16) float colmax[4][NL][36];   // 18 KB, wave-private

    const __bf16* pa   = wsA + (size_t)im * 8192 + (size_t)lane * 8;
    const __bf16* csrc = wsB + (size_t)tb * NL * 4096 + (size_t)lane * 8;

    bf16x8 afrA[8], afrB[8];             // frags (mf*4+ks): 0..7 / 8..15
    bf16x8 b0[8], b1[8];
    gload8(afrA, pa);                    // 8  outstanding
    gload8(afrB, pa + 4096);             // 16
    gload8(b0, csrc);                    // 24

    const f32x4 z4 = (f32x4)(0.f);       // persistent zero C-operand

#define AF(mf, ks) ((mf) < 2 ? afrA[(mf) * 4 + (ks)] : afrB[((mf) - 2) * 4 + (ks)])

#define COMPUTE(bfr, t)                                                     \
    {                                                                       \
        f32x4 acc[4][2];                                                    \
        _Pragma("unroll")                                                   \
        for (int ks = 0; ks < 4; ++ks)                                      \
            _Pragma("unroll")                                               \
            for (int mf = 0; mf < 4; ++mf)                                  \
                _Pragma("unroll")                                           \
                for (int nf = 0; nf < 2; ++nf)                              \
                    acc[mf][nf] = __builtin_amdgcn_mfma_f32_16x16x32_bf16(  \
                        AF(mf, ks), bfr[nf * 4 + ks],                       \
                        ks == 0 ? z4 : acc[mf][nf], 0, 0, 0);               \
        /* C/D: col = lane&15, row = hi*4+reg; m = mf*16+row.              \
           mf 0..2 all valid; mf=3: m=48+hi*4+r -> hi==0 && r==0 only */   \
        _Pragma("unroll")                                                   \
        for (int nf = 0; nf < 2; ++nf) {                                    \
            float p0 = fmaxf(fmaxf(acc[0][nf][0], acc[0][nf][1]),           \
                             fmaxf(acc[0][nf][2], acc[0][nf][3]));          \
            float p1 = fmaxf(fmaxf(acc[1][nf][0], acc[1][nf][1]),           \
                             fmaxf(acc[1][nf][2], acc[1][nf][3]));          \
            float p2 = fmaxf(fmaxf(acc[2][nf][0], acc[2][nf][1]),           \
                             fmaxf(acc[2][nf][2], acc[2][nf][3]));          \
            float p3 = (hi == 0) ? acc[3][nf][0] : NEG_INF;                 \
            float cm = fmaxf(fmaxf(p0, p1), fmaxf(p2, p3));                 \
            cm = fmaxf(cm, __shfl_xor(cm, 16));                             \
            cm = fmaxf(cm, __shfl_xor(cm, 32));                             \
            if (hi == 0) colmax[wave][t][nf * 16 + lo] = cm;                \
        }                                                                   \
    }

    #pragma unroll 1
    for (int it = 0; it < 15; ++it) {
        const int t = 2 * it;
        gload8(b1, csrc + (size_t)(t + 1) * 4096);
        VMWAIT8                          // b0 (and at it=0, afr) ready
        COMPUTE(b0, t)
        gload8(b0, csrc + (size_t)(t + 2) * 4096);
        VMWAIT8                          // b1 ready
        COMPUTE(b1, t + 1)
    }
    gload8(b1, csrc + (size_t)31 * 4096);
    VMWAIT8
    COMPUTE(b0, 30)
    VMWAIT0
    COMPUTE(b1, 31)
#undef COMPUTE
#undef AF

    // ---- epilogue: sum 32 cols per (text); write both mirrors ----
    {
        const float scale = expf(nlt[0]);
        const int t = ml;                    // text within chunk
        const float* r0 = &colmax[wave][t][h * 16];   // this half's 16 cols
        float4 a0 = *(const float4*)(r0 + 0);
        float4 a1 = *(const float4*)(r0 + 4);
        float4 a2 = *(const float4*)(r0 + 8);
        float4 a3 = *(const float4*)(r0 + 12);
        float s = ((a0.x + a0.y) + (a0.z + a0.w))
                + ((a1.x + a1.y) + (a1.z + a1.w))
                + ((a2.x + a2.y) + (a2.z + a2.w))
                + ((a3.x + a3.y) + (a3.z + a3.w));
        s += __shfl_xor(s, 32);              // other 16-col half
        if (h == 0) {
            int tg = tb * NL + t;
            float v = s * scale / (float)tlen[tg];
            out[im * NT + tg] = v;              // logits_per_image[i,t]
            out[NI * NT + tg * NI + im] = v;    // logits_per_text[t,i]
        }
    }
}

extern "C" void kernel_launch(void* const* d_in, const int* in_sizes, int n_in,
                              void* d_out, int out_size, void* d_ws, size_t ws_size,
                              hipStream_t stream)
{
    const float* img  = (const float*)d_in[0];
    const float* txt  = (const float*)d_in[1];
    const int*   tlen = (const int*)d_in[2];
    const float* nlt  = (const float*)d_in[3];
    float* out = (float*)d_out;

    __bf16* wsA = (__bf16*)d_ws;                 // 4 MB
    __bf16* wsB = wsA + (size_t)4096 * 512;      // 2 MB

    prep_kernel<<<dim3(1536), dim3(256), 0, stream>>>(img, txt, wsA, wsB);
    clip_match_kernel<<<dim3(512), dim3(256), 0, stream>>>(wsA, wsB, tlen, nlt, out);
}